// Round 6
// baseline (77.014 us; speedup 1.0000x reference)
//
#include <hip/hip_runtime.h>
#include <hip/hip_bf16.h>
#include <stdint.h>

#define H 128
#define NU 100000
#define NI 50000

typedef __attribute__((ext_vector_type(8))) short short8;
typedef __attribute__((ext_vector_type(4))) float f32x4;

__device__ __forceinline__ uint16_t f2bf(float f) {
    uint32_t x = __float_as_uint(f);
    return (uint16_t)((x + 0x7fffu + ((x >> 16) & 1u)) >> 16);  // RNE
}
__device__ __forceinline__ uint32_t cvtpk(float lo, float hi) {
    uint32_t r;
    asm("v_cvt_pk_bf16_f32 %0, %1, %2" : "=v"(r) : "v"(lo), "v"(hi));
    return r;
}
__device__ __forceinline__ float cvt_ub0(uint32_t v) { float f; asm("v_cvt_f32_ubyte0 %0, %1" : "=v"(f) : "v"(v)); return f; }
__device__ __forceinline__ float cvt_ub1(uint32_t v) { float f; asm("v_cvt_f32_ubyte1 %0, %1" : "=v"(f) : "v"(v)); return f; }
__device__ __forceinline__ float cvt_ub2(uint32_t v) { float f; asm("v_cvt_f32_ubyte2 %0, %1" : "=v"(f) : "v"(v)); return f; }
__device__ __forceinline__ float cvt_ub3(uint32_t v) { float f; asm("v_cvt_f32_ubyte3 %0, %1" : "=v"(f) : "v"(v)); return f; }

// Swizzled byte offset into a [128][128] bf16 LDS tile (XOR bank swizzle).
__device__ __forceinline__ int lds_off(int row, int k) {
    return (row * 256 + k * 2) ^ ((row & 7) << 4);
}

// Tables are per-row-scaled biased int8, PERMUTED columns: byte position
// p = lr*8 + n0 holds column n0*16 + lr.  value = scale * (q - 128).
// Edge lane t reads bytes [t*8, t*8+8) = columns {j*16+t}, j=0..7.

// One-time: W1 [2H][H] f32 (k-major) -> Wt [2][H n][H k] bf16 (n-major).
__global__ __launch_bounds__(256) void wconv_kernel(
    const float* __restrict__ W1, uint16_t* __restrict__ Wt)
{
    __shared__ char lds[32768];
    const int half = blockIdx.x;
    const float* W = W1 + (size_t)half * H * H;
    uint16_t* Out = Wt + (size_t)half * H * H;
    const int tid = threadIdx.x;

    int n4 = (tid & 31) * 4;
    int k  = tid >> 5;
    #pragma unroll
    for (int p = 0; p < 16; ++p, k += 8) {
        f32x4 v = *(const f32x4*)(W + (size_t)k * H + n4);
        *(uint16_t*)(lds + lds_off(n4 + 0, k)) = f2bf(v.x);
        *(uint16_t*)(lds + lds_off(n4 + 1, k)) = f2bf(v.y);
        *(uint16_t*)(lds + lds_off(n4 + 2, k)) = f2bf(v.z);
        *(uint16_t*)(lds + lds_off(n4 + 3, k)) = f2bf(v.w);
    }
    __syncthreads();
    int n = tid >> 1;
    #pragma unroll
    for (int p = 0; p < 8; ++p) {
        int chunk = (tid & 1) * 8 + p;
        uint4 v = *(const uint4*)(lds + lds_off(n, chunk * 8));
        *(uint4*)(Out + (size_t)n * H + chunk * 8) = v;
    }
}

// Project 128 rows/block, quantize each output row to int8 with per-row scale.
__global__ __launch_bounds__(256) void proj_kernel(
    const float* __restrict__ z_user, const float* __restrict__ z_item,
    const uint16_t* __restrict__ Wt, const float* __restrict__ b1,
    uint8_t* __restrict__ U8, uint8_t* __restrict__ I8,
    float* __restrict__ Us, float* __restrict__ Is, int nub)
{
    __shared__ char lds[32768];

    int bid = blockIdx.x;
    const float* Z; const uint16_t* Wth; uint8_t* Out8; float* Sc; int M; bool addb1;
    if (bid < nub) { Z = z_user; Wth = Wt;         Out8 = U8; Sc = Us; M = NU; addb1 = false; }
    else { bid -= nub; Z = z_item; Wth = Wt + H*H; Out8 = I8; Sc = Is; M = NI; addb1 = true; }
    const int row0 = bid * 128;
    const int tid = threadIdx.x;

    // Stage B: Wt half (bf16 [n][k]) -> LDS, swizzled, vector all the way.
    {
        int n = tid >> 1;
        #pragma unroll
        for (int p = 0; p < 8; ++p) {
            int chunk = (tid & 1) * 8 + p;
            uint4 v = *(const uint4*)(Wth + (size_t)n * H + chunk * 8);
            *(uint4*)(lds + lds_off(n, chunk * 8)) = v;
        }
    }
    __syncthreads();

    const int w  = tid >> 6;       // wave 0..3 -> rows 32w..32w+31
    const int l  = tid & 63;
    const int lr = l & 15;
    const int lk = (l >> 4) * 8;

    int r0 = row0 + w * 32 + lr;
    int r1 = r0 + 16;
    const float* a0p = Z + (size_t)(r0 < M ? r0 : M - 1) * H;
    const float* a1p = Z + (size_t)(r1 < M ? r1 : M - 1) * H;

    f32x4 acc[2][8];
    #pragma unroll
    for (int m0 = 0; m0 < 2; ++m0)
        #pragma unroll
        for (int n0 = 0; n0 < 8; ++n0)
            acc[m0][n0] = (f32x4){0.f, 0.f, 0.f, 0.f};

    #pragma unroll
    for (int kk = 0; kk < 4; ++kk) {
        int kb = kk * 32 + lk;
        f32x4 v00 = *(const f32x4*)(a0p + kb);
        f32x4 v01 = *(const f32x4*)(a0p + kb + 4);
        f32x4 v10 = *(const f32x4*)(a1p + kb);
        f32x4 v11 = *(const f32x4*)(a1p + kb + 4);
        short8 a0, a1;
        uint32_t* A0 = (uint32_t*)&a0;
        uint32_t* A1 = (uint32_t*)&a1;
        A0[0] = cvtpk(v00.x, v00.y); A0[1] = cvtpk(v00.z, v00.w);
        A0[2] = cvtpk(v01.x, v01.y); A0[3] = cvtpk(v01.z, v01.w);
        A1[0] = cvtpk(v10.x, v10.y); A1[1] = cvtpk(v10.z, v10.w);
        A1[2] = cvtpk(v11.x, v11.y); A1[3] = cvtpk(v11.z, v11.w);
        #pragma unroll
        for (int n0 = 0; n0 < 8; ++n0) {
            short8 b = *(const short8*)(lds + lds_off(n0*16 + lr, kb));
            acc[0][n0] = __builtin_amdgcn_mfma_f32_16x16x32_bf16(a0, b, acc[0][n0], 0, 0, 0);
            acc[1][n0] = __builtin_amdgcn_mfma_f32_16x16x32_bf16(a1, b, acc[1][n0], 0, 0, 0);
        }
    }

    float b1v[8];
    #pragma unroll
    for (int n0 = 0; n0 < 8; ++n0) b1v[n0] = addb1 ? b1[n0*16 + lr] : 0.f;

    // Quantizing epilogue. C/D: col = lane&15, row = (lane>>4)*4 + ri.
    const int rbase = row0 + w * 32;
    #pragma unroll
    for (int m0 = 0; m0 < 2; ++m0) {
        #pragma unroll
        for (int ri = 0; ri < 4; ++ri) {
            int gr = rbase + m0*16 + (l >> 4) * 4 + ri;
            float v[8];
            float am = 0.f;
            #pragma unroll
            for (int n0 = 0; n0 < 8; ++n0) {
                v[n0] = acc[m0][n0][ri] + b1v[n0];
                am = fmaxf(am, fabsf(v[n0]));
            }
            am = fmaxf(am, __shfl_xor(am, 1));
            am = fmaxf(am, __shfl_xor(am, 2));
            am = fmaxf(am, __shfl_xor(am, 4));
            am = fmaxf(am, __shfl_xor(am, 8));
            float s = am * (1.0f / 127.0f);
            float r = 127.0f / fmaxf(am, 1e-30f);
            uint32_t lo = 0, hi = 0;
            #pragma unroll
            for (int n0 = 0; n0 < 4; ++n0) {
                uint32_t q8 = (uint32_t)fmaf(v[n0], r, 128.5f);      // 1..255
                lo |= q8 << (8 * n0);
            }
            #pragma unroll
            for (int n0 = 4; n0 < 8; ++n0) {
                uint32_t q8 = (uint32_t)fmaf(v[n0], r, 128.5f);
                hi |= q8 << (8 * (n0 - 4));
            }
            if (gr < M) {
                *(uint2*)(Out8 + (size_t)gr * H + lr * 8) = make_uint2(lo, hi);
                if (lr == 0) Sc[gr] = s;
            }
        }
    }
}

// out[e] = relu(su*(qU-128) + si*(qI-128)) . W2 + b2   (b1 pre-folded into I)
__device__ __forceinline__ float edge_dot8(uint2 u, uint2 i, float su, float si,
                                           const float* w2v) {
    float k = -128.0f * (su + si);
    float acc = 0.f, h;
    h = fmaf(su, cvt_ub0(u.x), fmaf(si, cvt_ub0(i.x), k)); acc = fmaf(fmaxf(h, 0.f), w2v[0], acc);
    h = fmaf(su, cvt_ub1(u.x), fmaf(si, cvt_ub1(i.x), k)); acc = fmaf(fmaxf(h, 0.f), w2v[1], acc);
    h = fmaf(su, cvt_ub2(u.x), fmaf(si, cvt_ub2(i.x), k)); acc = fmaf(fmaxf(h, 0.f), w2v[2], acc);
    h = fmaf(su, cvt_ub3(u.x), fmaf(si, cvt_ub3(i.x), k)); acc = fmaf(fmaxf(h, 0.f), w2v[3], acc);
    h = fmaf(su, cvt_ub0(u.y), fmaf(si, cvt_ub0(i.y), k)); acc = fmaf(fmaxf(h, 0.f), w2v[4], acc);
    h = fmaf(su, cvt_ub1(u.y), fmaf(si, cvt_ub1(i.y), k)); acc = fmaf(fmaxf(h, 0.f), w2v[5], acc);
    h = fmaf(su, cvt_ub2(u.y), fmaf(si, cvt_ub2(i.y), k)); acc = fmaf(fmaxf(h, 0.f), w2v[6], acc);
    h = fmaf(su, cvt_ub3(u.y), fmaf(si, cvt_ub3(i.y), k)); acc = fmaf(fmaxf(h, 0.f), w2v[7], acc);
    return acc;
}

__device__ __forceinline__ float group_reduce(float acc) {
    acc += __shfl_xor(acc, 8);
    acc += __shfl_xor(acc, 4);
    acc += __shfl_xor(acc, 2);
    acc += __shfl_xor(acc, 1);
    return acc;
}

// Software-pipelined edge kernel: idx prefetched 2 iters ahead, gathers
// double-buffered 1 iter ahead -> steady state exposes no memory latency.
#define IDX_LOAD(ra, rb, ca, cb, e) do {              \
    ra = *(const int4*)(row_idx + (e));               \
    rb = *(const int4*)(row_idx + (e) + 4);           \
    ca = *(const int4*)(col_idx + (e));               \
    cb = *(const int4*)(col_idx + (e) + 4);           \
} while (0)

#define GATH(uu, ii, su, si, ra, rb, ca, cb) do {                      \
    int rr_[8] = {ra.x, ra.y, ra.z, ra.w, rb.x, rb.y, rb.z, rb.w};     \
    int cc_[8] = {ca.x, ca.y, ca.z, ca.w, cb.x, cb.y, cb.z, cb.w};     \
    _Pragma("unroll") for (int q = 0; q < 8; ++q) {                    \
        uu[q] = *(const uint2*)(U8 + (size_t)rr_[q] * H + t * 8);      \
        ii[q] = *(const uint2*)(I8 + (size_t)cc_[q] * H + t * 8); }    \
    _Pragma("unroll") for (int q = 0; q < 8; ++q) {                    \
        su[q] = Us[rr_[q]]; si[q] = Is[cc_[q]]; }                      \
} while (0)

#define COMPUTE(uu, ii, su, si, e) do {                                \
    float a_[8];                                                       \
    _Pragma("unroll") for (int q = 0; q < 8; ++q)                      \
        a_[q] = group_reduce(edge_dot8(uu[q], ii[q], su[q], si[q], w2v)); \
    if (t == 0) {                                                      \
        f32x4 o0; o0.x=a_[0]+b2; o0.y=a_[1]+b2; o0.z=a_[2]+b2; o0.w=a_[3]+b2; \
        f32x4 o1; o1.x=a_[4]+b2; o1.y=a_[5]+b2; o1.z=a_[6]+b2; o1.w=a_[7]+b2; \
        *(f32x4*)(out + (e)) = o0; *(f32x4*)(out + (e) + 4) = o1; }    \
} while (0)

__global__ __launch_bounds__(256) void edge_kernel(
    const uint8_t* __restrict__ U8, const uint8_t* __restrict__ I8,
    const float* __restrict__ Us, const float* __restrict__ Is,
    const int* __restrict__ row_idx, const int* __restrict__ col_idx,
    const float* __restrict__ W2, const float* __restrict__ b2p,
    float* __restrict__ out, int E)
{
    const int l = threadIdx.x & 63;
    const int g = l >> 4;
    const int t = l & 15;

    float w2v[8];
    #pragma unroll
    for (int j = 0; j < 8; ++j) w2v[j] = W2[j * 16 + t];  // permuted layout
    const float b2 = *b2p;

    const int wid = (int)((blockIdx.x * blockDim.x + threadIdx.x) >> 6);
    const int nw  = (int)((gridDim.x * blockDim.x) >> 6);
    const int stride = nw * 32;          // 8 edges per group, 4 groups per wave
    const int e0 = wid * 32 + g * 8;
    const int niter = (e0 + 7 < E) ? (int)((E - 8 - e0) / stride) + 1 : 0;

    uint2 uuP[8], iiP[8]; float suP[8], siP[8];
    uint2 uuQ[8], iiQ[8]; float suQ[8], siQ[8];
    int4 rA0, rA1, cA0, cA1, rB0, rB1, cB0, cB1;

    if (niter > 0) {
        int e = e0;
        IDX_LOAD(rA0, rA1, cA0, cA1, e);
        GATH(uuP, iiP, suP, siP, rA0, rA1, cA0, cA1);     // prologue stall ok
        if (niter > 1) IDX_LOAD(rB0, rB1, cB0, cB1, e + stride);
        int n = 0;
        while (true) {
            if (n + 1 < niter) GATH(uuQ, iiQ, suQ, siQ, rB0, rB1, cB0, cB1);
            if (n + 2 < niter) IDX_LOAD(rA0, rA1, cA0, cA1, e + 2 * stride);
            COMPUTE(uuP, iiP, suP, siP, e);
            if (++n >= niter) break;
            e += stride;
            if (n + 1 < niter) GATH(uuP, iiP, suP, siP, rA0, rA1, cA0, cA1);
            if (n + 2 < niter) IDX_LOAD(rB0, rB1, cB0, cB1, e + 2 * stride);
            COMPUTE(uuQ, iiQ, suQ, siQ, e);
            if (++n >= niter) break;
            e += stride;
        }
    }
    // tail (E % 8 != 0) — not hit for E = 1M
    if (wid == 0 && g == 0) {
        for (int e = (E & ~7); e < E; ++e) {
            int r = row_idx[e], c = col_idx[e];
            uint2 uv = *(const uint2*)(U8 + (size_t)r * H + t * 8);
            uint2 iv = *(const uint2*)(I8 + (size_t)c * H + t * 8);
            float acc = group_reduce(edge_dot8(uv, iv, Us[r], Is[c], w2v));
            if (t == 0) out[e] = acc + b2;
        }
    }
}

extern "C" void kernel_launch(void* const* d_in, const int* in_sizes, int n_in,
                              void* d_out, int out_size, void* d_ws, size_t ws_size,
                              hipStream_t stream) {
    const float* z_user = (const float*)d_in[0];
    const float* z_item = (const float*)d_in[1];
    const int*   row_idx = (const int*)d_in[2];
    const int*   col_idx = (const int*)d_in[3];
    const float* W1 = (const float*)d_in[4];
    const float* b1 = (const float*)d_in[5];
    const float* W2 = (const float*)d_in[6];
    const float* b2 = (const float*)d_in[7];
    float* out = (float*)d_out;
    const int E = in_sizes[2];

    uint8_t* U8 = (uint8_t*)d_ws;                   // 100000*128 = 12.8 MB
    uint8_t* I8 = U8 + (size_t)NU * H;              // 50000*128  =  6.4 MB
    float*   Us = (float*)(I8 + (size_t)NI * H);    // 400 KB
    float*   Is = Us + NU;                          // 200 KB
    uint16_t* Wt = (uint16_t*)(Is + NI);            // 64 KB (16B-aligned)

    const int nub = (NU + 127) / 128;  // 782
    const int nib = (NI + 127) / 128;  // 391
    wconv_kernel<<<2, 256, 0, stream>>>(W1, Wt);
    proj_kernel<<<nub + nib, 256, 0, stream>>>(z_user, z_item, Wt, b1, U8, I8, Us, Is, nub);
    edge_kernel<<<1024, 256, 0, stream>>>(U8, I8, Us, Is, row_idx, col_idx, W2, b2, out, E);
}

// Round 7
// 69.799 us; speedup vs baseline: 1.1034x; 1.1034x over previous
//
#include <hip/hip_runtime.h>
#include <hip/hip_bf16.h>
#include <stdint.h>

#define H 128
#define NU 100000
#define NI 50000

typedef __attribute__((ext_vector_type(8))) short short8;
typedef __attribute__((ext_vector_type(4))) float f32x4;

__device__ __forceinline__ uint16_t f2bf(float f) {
    uint32_t x = __float_as_uint(f);
    return (uint16_t)((x + 0x7fffu + ((x >> 16) & 1u)) >> 16);  // RNE
}
__device__ __forceinline__ uint32_t cvtpk(float lo, float hi) {
    uint32_t r;
    asm("v_cvt_pk_bf16_f32 %0, %1, %2" : "=v"(r) : "v"(lo), "v"(hi));
    return r;
}
__device__ __forceinline__ float cvt_ub0(uint32_t v) { float f; asm("v_cvt_f32_ubyte0 %0, %1" : "=v"(f) : "v"(v)); return f; }
__device__ __forceinline__ float cvt_ub1(uint32_t v) { float f; asm("v_cvt_f32_ubyte1 %0, %1" : "=v"(f) : "v"(v)); return f; }
__device__ __forceinline__ float cvt_ub2(uint32_t v) { float f; asm("v_cvt_f32_ubyte2 %0, %1" : "=v"(f) : "v"(v)); return f; }
__device__ __forceinline__ float cvt_ub3(uint32_t v) { float f; asm("v_cvt_f32_ubyte3 %0, %1" : "=v"(f) : "v"(v)); return f; }

// Swizzled byte offset into a [128][128] bf16 LDS tile (XOR bank swizzle).
__device__ __forceinline__ int lds_off(int row, int k) {
    return (row * 256 + k * 2) ^ ((row & 7) << 4);
}

// Tables are per-row-scaled biased int8, PERMUTED columns: byte position
// p = lr*8 + n0 holds column n0*16 + lr  (lr in [0,16), n0 in [0,8)).
// value = scale * (q - 128).
// Edge kernel uses 8-lane groups: lane t reads bytes [t*16, t*16+16) =
// cols { (j&7)*16 + 2t + (j>>3) : j=0..15 }.

// One-time: W1 [2H][H] f32 (k-major) -> Wt [2][H n][H k] bf16 (n-major).
__global__ __launch_bounds__(256) void wconv_kernel(
    const float* __restrict__ W1, uint16_t* __restrict__ Wt)
{
    __shared__ char lds[32768];
    const int half = blockIdx.x;
    const float* W = W1 + (size_t)half * H * H;
    uint16_t* Out = Wt + (size_t)half * H * H;
    const int tid = threadIdx.x;

    int n4 = (tid & 31) * 4;
    int k  = tid >> 5;
    #pragma unroll
    for (int p = 0; p < 16; ++p, k += 8) {
        f32x4 v = *(const f32x4*)(W + (size_t)k * H + n4);
        *(uint16_t*)(lds + lds_off(n4 + 0, k)) = f2bf(v.x);
        *(uint16_t*)(lds + lds_off(n4 + 1, k)) = f2bf(v.y);
        *(uint16_t*)(lds + lds_off(n4 + 2, k)) = f2bf(v.z);
        *(uint16_t*)(lds + lds_off(n4 + 3, k)) = f2bf(v.w);
    }
    __syncthreads();
    int n = tid >> 1;
    #pragma unroll
    for (int p = 0; p < 8; ++p) {
        int chunk = (tid & 1) * 8 + p;
        uint4 v = *(const uint4*)(lds + lds_off(n, chunk * 8));
        *(uint4*)(Out + (size_t)n * H + chunk * 8) = v;
    }
}

// Project 128 rows/block, quantize each output row to int8 with per-row scale.
__global__ __launch_bounds__(256) void proj_kernel(
    const float* __restrict__ z_user, const float* __restrict__ z_item,
    const uint16_t* __restrict__ Wt, const float* __restrict__ b1,
    uint8_t* __restrict__ U8, uint8_t* __restrict__ I8,
    float* __restrict__ Us, float* __restrict__ Is, int nub)
{
    __shared__ char lds[32768];

    int bid = blockIdx.x;
    const float* Z; const uint16_t* Wth; uint8_t* Out8; float* Sc; int M; bool addb1;
    if (bid < nub) { Z = z_user; Wth = Wt;         Out8 = U8; Sc = Us; M = NU; addb1 = false; }
    else { bid -= nub; Z = z_item; Wth = Wt + H*H; Out8 = I8; Sc = Is; M = NI; addb1 = true; }
    const int row0 = bid * 128;
    const int tid = threadIdx.x;

    // Stage B: Wt half (bf16 [n][k]) -> LDS, swizzled, vector all the way.
    {
        int n = tid >> 1;
        #pragma unroll
        for (int p = 0; p < 8; ++p) {
            int chunk = (tid & 1) * 8 + p;
            uint4 v = *(const uint4*)(Wth + (size_t)n * H + chunk * 8);
            *(uint4*)(lds + lds_off(n, chunk * 8)) = v;
        }
    }
    __syncthreads();

    const int w  = tid >> 6;       // wave 0..3 -> rows 32w..32w+31
    const int l  = tid & 63;
    const int lr = l & 15;
    const int lk = (l >> 4) * 8;

    int r0 = row0 + w * 32 + lr;
    int r1 = r0 + 16;
    const float* a0p = Z + (size_t)(r0 < M ? r0 : M - 1) * H;
    const float* a1p = Z + (size_t)(r1 < M ? r1 : M - 1) * H;

    f32x4 acc[2][8];
    #pragma unroll
    for (int m0 = 0; m0 < 2; ++m0)
        #pragma unroll
        for (int n0 = 0; n0 < 8; ++n0)
            acc[m0][n0] = (f32x4){0.f, 0.f, 0.f, 0.f};

    #pragma unroll
    for (int kk = 0; kk < 4; ++kk) {
        int kb = kk * 32 + lk;
        f32x4 v00 = *(const f32x4*)(a0p + kb);
        f32x4 v01 = *(const f32x4*)(a0p + kb + 4);
        f32x4 v10 = *(const f32x4*)(a1p + kb);
        f32x4 v11 = *(const f32x4*)(a1p + kb + 4);
        short8 a0, a1;
        uint32_t* A0 = (uint32_t*)&a0;
        uint32_t* A1 = (uint32_t*)&a1;
        A0[0] = cvtpk(v00.x, v00.y); A0[1] = cvtpk(v00.z, v00.w);
        A0[2] = cvtpk(v01.x, v01.y); A0[3] = cvtpk(v01.z, v01.w);
        A1[0] = cvtpk(v10.x, v10.y); A1[1] = cvtpk(v10.z, v10.w);
        A1[2] = cvtpk(v11.x, v11.y); A1[3] = cvtpk(v11.z, v11.w);
        #pragma unroll
        for (int n0 = 0; n0 < 8; ++n0) {
            short8 b = *(const short8*)(lds + lds_off(n0*16 + lr, kb));
            acc[0][n0] = __builtin_amdgcn_mfma_f32_16x16x32_bf16(a0, b, acc[0][n0], 0, 0, 0);
            acc[1][n0] = __builtin_amdgcn_mfma_f32_16x16x32_bf16(a1, b, acc[1][n0], 0, 0, 0);
        }
    }

    float b1v[8];
    #pragma unroll
    for (int n0 = 0; n0 < 8; ++n0) b1v[n0] = addb1 ? b1[n0*16 + lr] : 0.f;

    // Quantizing epilogue. C/D: col = lane&15, row = (lane>>4)*4 + ri.
    const int rbase = row0 + w * 32;
    #pragma unroll
    for (int m0 = 0; m0 < 2; ++m0) {
        #pragma unroll
        for (int ri = 0; ri < 4; ++ri) {
            int gr = rbase + m0*16 + (l >> 4) * 4 + ri;
            float v[8];
            float am = 0.f;
            #pragma unroll
            for (int n0 = 0; n0 < 8; ++n0) {
                v[n0] = acc[m0][n0][ri] + b1v[n0];
                am = fmaxf(am, fabsf(v[n0]));
            }
            am = fmaxf(am, __shfl_xor(am, 1));
            am = fmaxf(am, __shfl_xor(am, 2));
            am = fmaxf(am, __shfl_xor(am, 4));
            am = fmaxf(am, __shfl_xor(am, 8));
            float s = am * (1.0f / 127.0f);
            float r = 127.0f / fmaxf(am, 1e-30f);
            uint32_t lo = 0, hi = 0;
            #pragma unroll
            for (int n0 = 0; n0 < 4; ++n0) {
                uint32_t q8 = (uint32_t)fmaf(v[n0], r, 128.5f);      // 1..255
                lo |= q8 << (8 * n0);
            }
            #pragma unroll
            for (int n0 = 4; n0 < 8; ++n0) {
                uint32_t q8 = (uint32_t)fmaf(v[n0], r, 128.5f);
                hi |= q8 << (8 * (n0 - 4));
            }
            if (gr < M) {
                *(uint2*)(Out8 + (size_t)gr * H + lr * 8) = make_uint2(lo, hi);
                if (lr == 0) Sc[gr] = s;
            }
        }
    }
}

// out[e] = relu(su*(qU-128) + si*(qI-128)) . W2 + b2   (b1 pre-folded into I)
// 8 lanes per edge, 16 int8 elems (one dwordx4) per lane per table.
__device__ __forceinline__ float edge_dot16(uint4 u, uint4 i, float su, float si,
                                            const float* w2v) {
    const float k = -128.0f * (su + si);
    const uint32_t* up = &u.x;
    const uint32_t* ip = &i.x;
    float acc = 0.f, h;
    #pragma unroll
    for (int d = 0; d < 4; ++d) {
        h = fmaf(su, cvt_ub0(up[d]), fmaf(si, cvt_ub0(ip[d]), k)); acc = fmaf(fmaxf(h, 0.f), w2v[4*d+0], acc);
        h = fmaf(su, cvt_ub1(up[d]), fmaf(si, cvt_ub1(ip[d]), k)); acc = fmaf(fmaxf(h, 0.f), w2v[4*d+1], acc);
        h = fmaf(su, cvt_ub2(up[d]), fmaf(si, cvt_ub2(ip[d]), k)); acc = fmaf(fmaxf(h, 0.f), w2v[4*d+2], acc);
        h = fmaf(su, cvt_ub3(up[d]), fmaf(si, cvt_ub3(ip[d]), k)); acc = fmaf(fmaxf(h, 0.f), w2v[4*d+3], acc);
    }
    return acc;
}

__device__ __forceinline__ float group_reduce8(float acc) {
    acc += __shfl_xor(acc, 4);
    acc += __shfl_xor(acc, 2);
    acc += __shfl_xor(acc, 1);
    return acc;
}

__global__ __launch_bounds__(256) void edge_kernel(
    const uint8_t* __restrict__ U8, const uint8_t* __restrict__ I8,
    const float* __restrict__ Us, const float* __restrict__ Is,
    const int* __restrict__ row_idx, const int* __restrict__ col_idx,
    const float* __restrict__ W2, const float* __restrict__ b2p,
    float* __restrict__ out, int E)
{
    const int l = threadIdx.x & 63;
    const int g = l >> 3;          // 8 groups of 8 lanes per wave
    const int t = l & 7;

    float w2v[16];
    #pragma unroll
    for (int j = 0; j < 16; ++j) w2v[j] = W2[(j & 7) * 16 + 2 * t + (j >> 3)];
    const float b2 = *b2p;

    const int wid = (int)((blockIdx.x * blockDim.x + threadIdx.x) >> 6);
    const int nw  = (int)((gridDim.x * blockDim.x) >> 6);
    const int stride = nw * 32;    // 4 edges per group, 8 groups per wave
    const int toff = t * 16;

    for (int e0 = wid * 32 + g * 4; e0 + 3 < E; e0 += stride) {
        int4 rp = *(const int4*)(row_idx + e0);
        int4 cp = *(const int4*)(col_idx + e0);
        uint4 u0 = *(const uint4*)(U8 + (uint32_t)(rp.x * H + toff));
        uint4 i0 = *(const uint4*)(I8 + (uint32_t)(cp.x * H + toff));
        uint4 u1 = *(const uint4*)(U8 + (uint32_t)(rp.y * H + toff));
        uint4 i1 = *(const uint4*)(I8 + (uint32_t)(cp.y * H + toff));
        uint4 u2 = *(const uint4*)(U8 + (uint32_t)(rp.z * H + toff));
        uint4 i2 = *(const uint4*)(I8 + (uint32_t)(cp.z * H + toff));
        uint4 u3 = *(const uint4*)(U8 + (uint32_t)(rp.w * H + toff));
        uint4 i3 = *(const uint4*)(I8 + (uint32_t)(cp.w * H + toff));
        float su0 = Us[rp.x], si0 = Is[cp.x];
        float su1 = Us[rp.y], si1 = Is[cp.y];
        float su2 = Us[rp.z], si2 = Is[cp.z];
        float su3 = Us[rp.w], si3 = Is[cp.w];
        float a0 = group_reduce8(edge_dot16(u0, i0, su0, si0, w2v));
        float a1 = group_reduce8(edge_dot16(u1, i1, su1, si1, w2v));
        float a2 = group_reduce8(edge_dot16(u2, i2, su2, si2, w2v));
        float a3 = group_reduce8(edge_dot16(u3, i3, su3, si3, w2v));
        if (t == 0) {
            f32x4 o; o.x = a0 + b2; o.y = a1 + b2; o.z = a2 + b2; o.w = a3 + b2;
            *(f32x4*)(out + e0) = o;
        }
    }
    // tail (E % 4 != 0) — not hit for E = 1M
    if (wid == 0 && g == 0) {
        for (int e = (E & ~3); e < E; ++e) {
            int r = row_idx[e], c = col_idx[e];
            uint4 uv = *(const uint4*)(U8 + (uint32_t)(r * H + toff));
            uint4 iv = *(const uint4*)(I8 + (uint32_t)(c * H + toff));
            float acc = group_reduce8(edge_dot16(uv, iv, Us[r], Is[c], w2v));
            if (t == 0) out[e] = acc + b2;
        }
    }
}

extern "C" void kernel_launch(void* const* d_in, const int* in_sizes, int n_in,
                              void* d_out, int out_size, void* d_ws, size_t ws_size,
                              hipStream_t stream) {
    const float* z_user = (const float*)d_in[0];
    const float* z_item = (const float*)d_in[1];
    const int*   row_idx = (const int*)d_in[2];
    const int*   col_idx = (const int*)d_in[3];
    const float* W1 = (const float*)d_in[4];
    const float* b1 = (const float*)d_in[5];
    const float* W2 = (const float*)d_in[6];
    const float* b2 = (const float*)d_in[7];
    float* out = (float*)d_out;
    const int E = in_sizes[2];

    uint8_t* U8 = (uint8_t*)d_ws;                   // 100000*128 = 12.8 MB
    uint8_t* I8 = U8 + (size_t)NU * H;              // 50000*128  =  6.4 MB
    float*   Us = (float*)(I8 + (size_t)NI * H);    // 400 KB
    float*   Is = Us + NU;                          // 200 KB
    uint16_t* Wt = (uint16_t*)(Is + NI);            // 64 KB (16B-aligned)

    const int nub = (NU + 127) / 128;  // 782
    const int nib = (NI + 127) / 128;  // 391
    wconv_kernel<<<2, 256, 0, stream>>>(W1, Wt);
    proj_kernel<<<nub + nib, 256, 0, stream>>>(z_user, z_item, Wt, b1, U8, I8, Us, Is, nub);
    edge_kernel<<<2048, 256, 0, stream>>>(U8, I8, Us, Is, row_idx, col_idx, W2, b2, out, E);
}

// Round 8
// 64.235 us; speedup vs baseline: 1.1989x; 1.0866x over previous
//
#include <hip/hip_runtime.h>
#include <hip/hip_bf16.h>
#include <stdint.h>

#define H 128
#define NU 100000
#define NI 50000

typedef __attribute__((ext_vector_type(8))) short short8;
typedef __attribute__((ext_vector_type(4))) float f32x4;

__device__ __forceinline__ uint16_t f2bf(float f) {
    uint32_t x = __float_as_uint(f);
    return (uint16_t)((x + 0x7fffu + ((x >> 16) & 1u)) >> 16);  // RNE
}
__device__ __forceinline__ uint32_t cvtpk(float lo, float hi) {
    uint32_t r;
    asm("v_cvt_pk_bf16_f32 %0, %1, %2" : "=v"(r) : "v"(lo), "v"(hi));
    return r;
}
__device__ __forceinline__ float cvt_ub0(uint32_t v) { float f; asm("v_cvt_f32_ubyte0 %0, %1" : "=v"(f) : "v"(v)); return f; }
__device__ __forceinline__ float cvt_ub1(uint32_t v) { float f; asm("v_cvt_f32_ubyte1 %0, %1" : "=v"(f) : "v"(v)); return f; }
__device__ __forceinline__ float cvt_ub2(uint32_t v) { float f; asm("v_cvt_f32_ubyte2 %0, %1" : "=v"(f) : "v"(v)); return f; }
__device__ __forceinline__ float cvt_ub3(uint32_t v) { float f; asm("v_cvt_f32_ubyte3 %0, %1" : "=v"(f) : "v"(v)); return f; }

// Swizzled byte offset into a [128][128] bf16 LDS tile (XOR bank swizzle).
__device__ __forceinline__ int lds_off(int row, int k) {
    return (row * 256 + k * 2) ^ ((row & 7) << 4);
}

// Tables are per-row-scaled biased int8, PERMUTED columns: byte position
// p = lr*8 + n0 holds column n0*16 + lr  (lr in [0,16), n0 in [0,8)).
// value = scale * (q - 128).
// Edge kernel uses 8-lane groups: lane t reads bytes [t*16, t*16+16) =
// cols { (j&7)*16 + 2t + (j>>3) : j=0..15 }.

// One-time: W1 [2H][H] f32 (k-major) -> Wt [2][H n][H k] bf16 (n-major).
__global__ __launch_bounds__(256) void wconv_kernel(
    const float* __restrict__ W1, uint16_t* __restrict__ Wt)
{
    __shared__ char lds[32768];
    const int half = blockIdx.x;
    const float* W = W1 + (size_t)half * H * H;
    uint16_t* Out = Wt + (size_t)half * H * H;
    const int tid = threadIdx.x;

    int n4 = (tid & 31) * 4;
    int k  = tid >> 5;
    #pragma unroll
    for (int p = 0; p < 16; ++p, k += 8) {
        f32x4 v = *(const f32x4*)(W + (size_t)k * H + n4);
        *(uint16_t*)(lds + lds_off(n4 + 0, k)) = f2bf(v.x);
        *(uint16_t*)(lds + lds_off(n4 + 1, k)) = f2bf(v.y);
        *(uint16_t*)(lds + lds_off(n4 + 2, k)) = f2bf(v.z);
        *(uint16_t*)(lds + lds_off(n4 + 3, k)) = f2bf(v.w);
    }
    __syncthreads();
    int n = tid >> 1;
    #pragma unroll
    for (int p = 0; p < 8; ++p) {
        int chunk = (tid & 1) * 8 + p;
        uint4 v = *(const uint4*)(lds + lds_off(n, chunk * 8));
        *(uint4*)(Out + (size_t)n * H + chunk * 8) = v;
    }
}

// Project 128 rows/block with 8 waves (16 rows/wave), quantize each output
// row to int8 with per-row scale. 512 threads: half the per-wave VGPR of the
// 4-wave version -> ~2x resident waves for latency hiding.
__global__ __launch_bounds__(512) void proj_kernel(
    const float* __restrict__ z_user, const float* __restrict__ z_item,
    const uint16_t* __restrict__ Wt, const float* __restrict__ b1,
    uint8_t* __restrict__ U8, uint8_t* __restrict__ I8,
    float* __restrict__ Us, float* __restrict__ Is, int nub)
{
    __shared__ char lds[32768];

    int bid = blockIdx.x;
    const float* Z; const uint16_t* Wth; uint8_t* Out8; float* Sc; int M; bool addb1;
    if (bid < nub) { Z = z_user; Wth = Wt;         Out8 = U8; Sc = Us; M = NU; addb1 = false; }
    else { bid -= nub; Z = z_item; Wth = Wt + H*H; Out8 = I8; Sc = Is; M = NI; addb1 = true; }
    const int row0 = bid * 128;
    const int tid = threadIdx.x;

    // Stage B: Wt half (bf16 [n][k]) -> LDS, swizzled. 512 threads, 64B each.
    {
        int n = tid >> 2;
        #pragma unroll
        for (int p = 0; p < 4; ++p) {
            int chunk = (tid & 3) * 4 + p;
            uint4 v = *(const uint4*)(Wth + (size_t)n * H + chunk * 8);
            *(uint4*)(lds + lds_off(n, chunk * 8)) = v;
        }
    }
    __syncthreads();

    const int w  = tid >> 6;       // wave 0..7 -> rows 16w..16w+15
    const int l  = tid & 63;
    const int lr = l & 15;
    const int lk = (l >> 4) * 8;

    int r0 = row0 + w * 16 + lr;
    const float* a0p = Z + (size_t)(r0 < M ? r0 : M - 1) * H;

    f32x4 acc[8];
    #pragma unroll
    for (int n0 = 0; n0 < 8; ++n0)
        acc[n0] = (f32x4){0.f, 0.f, 0.f, 0.f};

    #pragma unroll
    for (int kk = 0; kk < 4; ++kk) {
        int kb = kk * 32 + lk;
        f32x4 v00 = *(const f32x4*)(a0p + kb);
        f32x4 v01 = *(const f32x4*)(a0p + kb + 4);
        short8 a0;
        uint32_t* A0 = (uint32_t*)&a0;
        A0[0] = cvtpk(v00.x, v00.y); A0[1] = cvtpk(v00.z, v00.w);
        A0[2] = cvtpk(v01.x, v01.y); A0[3] = cvtpk(v01.z, v01.w);
        #pragma unroll
        for (int n0 = 0; n0 < 8; ++n0) {
            short8 b = *(const short8*)(lds + lds_off(n0*16 + lr, kb));
            acc[n0] = __builtin_amdgcn_mfma_f32_16x16x32_bf16(a0, b, acc[n0], 0, 0, 0);
        }
    }

    float b1v[8];
    #pragma unroll
    for (int n0 = 0; n0 < 8; ++n0) b1v[n0] = addb1 ? b1[n0*16 + lr] : 0.f;

    // Quantizing epilogue. C/D: col = lane&15, row = (lane>>4)*4 + ri.
    const int rbase = row0 + w * 16;
    #pragma unroll
    for (int ri = 0; ri < 4; ++ri) {
        int gr = rbase + (l >> 4) * 4 + ri;
        float v[8];
        float am = 0.f;
        #pragma unroll
        for (int n0 = 0; n0 < 8; ++n0) {
            v[n0] = acc[n0][ri] + b1v[n0];
            am = fmaxf(am, fabsf(v[n0]));
        }
        am = fmaxf(am, __shfl_xor(am, 1));
        am = fmaxf(am, __shfl_xor(am, 2));
        am = fmaxf(am, __shfl_xor(am, 4));
        am = fmaxf(am, __shfl_xor(am, 8));
        float s = am * (1.0f / 127.0f);
        float r = 127.0f / fmaxf(am, 1e-30f);
        uint32_t lo = 0, hi = 0;
        #pragma unroll
        for (int n0 = 0; n0 < 4; ++n0) {
            uint32_t q8 = (uint32_t)fmaf(v[n0], r, 128.5f);          // 1..255
            lo |= q8 << (8 * n0);
        }
        #pragma unroll
        for (int n0 = 4; n0 < 8; ++n0) {
            uint32_t q8 = (uint32_t)fmaf(v[n0], r, 128.5f);
            hi |= q8 << (8 * (n0 - 4));
        }
        if (gr < M) {
            *(uint2*)(Out8 + (size_t)gr * H + lr * 8) = make_uint2(lo, hi);
            if (lr == 0) Sc[gr] = s;
        }
    }
}

// out[e] = relu(su*(qU-128) + si*(qI-128)) . W2 + b2   (b1 pre-folded into I)
// 8 lanes per edge, 16 int8 elems (one dwordx4) per lane per table.
// Indices prefetched one iteration ahead so gathers issue without an
// idx-load wait (only +8 VGPR — keeps 8 waves/SIMD, unlike the R6 pipeline).
__device__ __forceinline__ float edge_dot16(uint4 u, uint4 i, float su, float si,
                                            const float* w2v) {
    const float k = -128.0f * (su + si);
    const uint32_t* up = &u.x;
    const uint32_t* ip = &i.x;
    float acc = 0.f, h;
    #pragma unroll
    for (int d = 0; d < 4; ++d) {
        h = fmaf(su, cvt_ub0(up[d]), fmaf(si, cvt_ub0(ip[d]), k)); acc = fmaf(fmaxf(h, 0.f), w2v[4*d+0], acc);
        h = fmaf(su, cvt_ub1(up[d]), fmaf(si, cvt_ub1(ip[d]), k)); acc = fmaf(fmaxf(h, 0.f), w2v[4*d+1], acc);
        h = fmaf(su, cvt_ub2(up[d]), fmaf(si, cvt_ub2(ip[d]), k)); acc = fmaf(fmaxf(h, 0.f), w2v[4*d+2], acc);
        h = fmaf(su, cvt_ub3(up[d]), fmaf(si, cvt_ub3(ip[d]), k)); acc = fmaf(fmaxf(h, 0.f), w2v[4*d+3], acc);
    }
    return acc;
}

__device__ __forceinline__ float group_reduce8(float acc) {
    acc += __shfl_xor(acc, 4);
    acc += __shfl_xor(acc, 2);
    acc += __shfl_xor(acc, 1);
    return acc;
}

__global__ __launch_bounds__(256) void edge_kernel(
    const uint8_t* __restrict__ U8, const uint8_t* __restrict__ I8,
    const float* __restrict__ Us, const float* __restrict__ Is,
    const int* __restrict__ row_idx, const int* __restrict__ col_idx,
    const float* __restrict__ W2, const float* __restrict__ b2p,
    float* __restrict__ out, int E)
{
    const int l = threadIdx.x & 63;
    const int g = l >> 3;          // 8 groups of 8 lanes per wave
    const int t = l & 7;

    float w2v[16];
    #pragma unroll
    for (int j = 0; j < 16; ++j) w2v[j] = W2[(j & 7) * 16 + 2 * t + (j >> 3)];
    const float b2 = *b2p;

    const int wid = (int)((blockIdx.x * blockDim.x + threadIdx.x) >> 6);
    const int nw  = (int)((gridDim.x * blockDim.x) >> 6);
    const int stride = nw * 32;    // 4 edges per group, 8 groups per wave
    const int toff = t * 16;
    const int e0 = wid * 32 + g * 4;

    if (e0 + 3 < E) {
        int4 rp = *(const int4*)(row_idx + e0);
        int4 cp = *(const int4*)(col_idx + e0);
        for (int e = e0; e + 3 < E; e += stride) {
            // prefetch next iteration's indices (independent of this iter)
            int en = e + stride;
            int4 rpn = rp, cpn = cp;
            if (en + 3 < E) {
                rpn = *(const int4*)(row_idx + en);
                cpn = *(const int4*)(col_idx + en);
            }
            uint4 u0 = *(const uint4*)(U8 + (uint32_t)(rp.x * H + toff));
            uint4 i0 = *(const uint4*)(I8 + (uint32_t)(cp.x * H + toff));
            uint4 u1 = *(const uint4*)(U8 + (uint32_t)(rp.y * H + toff));
            uint4 i1 = *(const uint4*)(I8 + (uint32_t)(cp.y * H + toff));
            uint4 u2 = *(const uint4*)(U8 + (uint32_t)(rp.z * H + toff));
            uint4 i2 = *(const uint4*)(I8 + (uint32_t)(cp.z * H + toff));
            uint4 u3 = *(const uint4*)(U8 + (uint32_t)(rp.w * H + toff));
            uint4 i3 = *(const uint4*)(I8 + (uint32_t)(cp.w * H + toff));
            float su0 = Us[rp.x], si0 = Is[cp.x];
            float su1 = Us[rp.y], si1 = Is[cp.y];
            float su2 = Us[rp.z], si2 = Is[cp.z];
            float su3 = Us[rp.w], si3 = Is[cp.w];
            float a0 = group_reduce8(edge_dot16(u0, i0, su0, si0, w2v));
            float a1 = group_reduce8(edge_dot16(u1, i1, su1, si1, w2v));
            float a2 = group_reduce8(edge_dot16(u2, i2, su2, si2, w2v));
            float a3 = group_reduce8(edge_dot16(u3, i3, su3, si3, w2v));
            if (t == 0) {
                f32x4 o; o.x = a0 + b2; o.y = a1 + b2; o.z = a2 + b2; o.w = a3 + b2;
                *(f32x4*)(out + e) = o;
            }
            rp = rpn; cp = cpn;
        }
    }
    // tail (E % 4 != 0) — not hit for E = 1M
    if (wid == 0 && g == 0) {
        for (int e = (E & ~3); e < E; ++e) {
            int r = row_idx[e], c = col_idx[e];
            uint4 uv = *(const uint4*)(U8 + (uint32_t)(r * H + toff));
            uint4 iv = *(const uint4*)(I8 + (uint32_t)(c * H + toff));
            float acc = group_reduce8(edge_dot16(uv, iv, Us[r], Is[c], w2v));
            if (t == 0) out[e] = acc + b2;
        }
    }
}

extern "C" void kernel_launch(void* const* d_in, const int* in_sizes, int n_in,
                              void* d_out, int out_size, void* d_ws, size_t ws_size,
                              hipStream_t stream) {
    const float* z_user = (const float*)d_in[0];
    const float* z_item = (const float*)d_in[1];
    const int*   row_idx = (const int*)d_in[2];
    const int*   col_idx = (const int*)d_in[3];
    const float* W1 = (const float*)d_in[4];
    const float* b1 = (const float*)d_in[5];
    const float* W2 = (const float*)d_in[6];
    const float* b2 = (const float*)d_in[7];
    float* out = (float*)d_out;
    const int E = in_sizes[2];

    uint8_t* U8 = (uint8_t*)d_ws;                   // 100000*128 = 12.8 MB
    uint8_t* I8 = U8 + (size_t)NU * H;              // 50000*128  =  6.4 MB
    float*   Us = (float*)(I8 + (size_t)NI * H);    // 400 KB
    float*   Is = Us + NU;                          // 200 KB
    uint16_t* Wt = (uint16_t*)(Is + NI);            // 64 KB (16B-aligned)

    const int nub = (NU + 127) / 128;  // 782
    const int nib = (NI + 127) / 128;  // 391
    wconv_kernel<<<2, 256, 0, stream>>>(W1, Wt);
    proj_kernel<<<nub + nib, 512, 0, stream>>>(z_user, z_item, Wt, b1, U8, I8, Us, Is, nub);
    edge_kernel<<<2048, 256, 0, stream>>>(U8, I8, Us, Is, row_idx, col_idx, W2, b2, out, E);
}

// Round 9
// 63.398 us; speedup vs baseline: 1.2148x; 1.0132x over previous
//
#include <hip/hip_runtime.h>
#include <hip/hip_bf16.h>
#include <stdint.h>

#define H 128
#define NU 100000
#define NI 50000

typedef __attribute__((ext_vector_type(8))) short short8;
typedef __attribute__((ext_vector_type(4))) float f32x4;
typedef __attribute__((ext_vector_type(2))) float f32x2;

__device__ __forceinline__ uint16_t f2bf(float f) {
    uint32_t x = __float_as_uint(f);
    return (uint16_t)((x + 0x7fffu + ((x >> 16) & 1u)) >> 16);  // RNE
}
__device__ __forceinline__ uint32_t cvtpk(float lo, float hi) {
    uint32_t r;
    asm("v_cvt_pk_bf16_f32 %0, %1, %2" : "=v"(r) : "v"(lo), "v"(hi));
    return r;
}
__device__ __forceinline__ float cvt_ub0(uint32_t v) { float f; asm("v_cvt_f32_ubyte0 %0, %1" : "=v"(f) : "v"(v)); return f; }
__device__ __forceinline__ float cvt_ub1(uint32_t v) { float f; asm("v_cvt_f32_ubyte1 %0, %1" : "=v"(f) : "v"(v)); return f; }
__device__ __forceinline__ float cvt_ub2(uint32_t v) { float f; asm("v_cvt_f32_ubyte2 %0, %1" : "=v"(f) : "v"(v)); return f; }
__device__ __forceinline__ float cvt_ub3(uint32_t v) { float f; asm("v_cvt_f32_ubyte3 %0, %1" : "=v"(f) : "v"(v)); return f; }
__device__ __forceinline__ f32x2 pk_fma(f32x2 a, f32x2 b, f32x2 c) {
    f32x2 d;
    asm("v_pk_fma_f32 %0, %1, %2, %3" : "=v"(d) : "v"(a), "v"(b), "v"(c));
    return d;
}

// Swizzled byte offset into a [128][128] bf16 LDS tile (XOR bank swizzle).
__device__ __forceinline__ int lds_off(int row, int k) {
    return (row * 256 + k * 2) ^ ((row & 7) << 4);
}

// Tables are per-row-scaled biased int8, PERMUTED columns: byte position
// p = lr*8 + n0 holds column n0*16 + lr  (lr in [0,16), n0 in [0,8)).
// value = scale * (q - 128).
// Edge kernel uses 8-lane groups: lane t reads bytes [t*16, t*16+16) =
// cols { (j&7)*16 + 2t + (j>>3) : j=0..15 }.

// One-time: W1 [2H][H] f32 (k-major) -> Wt [2][H n][H k] bf16 (n-major).
// 32 blocks (2 halves x 16 slices of 8 n-rows) so it finishes in <1 us.
__global__ __launch_bounds__(256) void wconv_kernel(
    const float* __restrict__ W1, uint16_t* __restrict__ Wt)
{
    __shared__ uint16_t lds[8][128];
    const int half = blockIdx.x >> 4;
    const int n8 = (blockIdx.x & 15) * 8;
    const float* W = W1 + (size_t)half * H * H;
    uint16_t* Out = Wt + (size_t)half * H * H;
    const int tid = threadIdx.x;

    int k = tid >> 1, noff = (tid & 1) * 4;
    f32x4 v = *(const f32x4*)(W + (size_t)k * H + n8 + noff);
    lds[noff + 0][k] = f2bf(v.x);
    lds[noff + 1][k] = f2bf(v.y);
    lds[noff + 2][k] = f2bf(v.z);
    lds[noff + 3][k] = f2bf(v.w);
    __syncthreads();
    int n = tid >> 5, c = (tid & 31) * 4;
    *(uint2*)(Out + (size_t)(n8 + n) * H + c) = *(const uint2*)&lds[n][c];
}

// Project 128 rows/block with 8 waves (16 rows/wave), quantize each output
// row to int8 with per-row scale.
__global__ __launch_bounds__(512) void proj_kernel(
    const float* __restrict__ z_user, const float* __restrict__ z_item,
    const uint16_t* __restrict__ Wt, const float* __restrict__ b1,
    uint8_t* __restrict__ U8, uint8_t* __restrict__ I8,
    float* __restrict__ Us, float* __restrict__ Is, int nub)
{
    __shared__ char lds[32768];

    int bid = blockIdx.x;
    const float* Z; const uint16_t* Wth; uint8_t* Out8; float* Sc; int M; bool addb1;
    if (bid < nub) { Z = z_user; Wth = Wt;         Out8 = U8; Sc = Us; M = NU; addb1 = false; }
    else { bid -= nub; Z = z_item; Wth = Wt + H*H; Out8 = I8; Sc = Is; M = NI; addb1 = true; }
    const int row0 = bid * 128;
    const int tid = threadIdx.x;

    // Stage B: Wt half (bf16 [n][k]) -> LDS, swizzled. 512 threads, 64B each.
    {
        int n = tid >> 2;
        #pragma unroll
        for (int p = 0; p < 4; ++p) {
            int chunk = (tid & 3) * 4 + p;
            uint4 v = *(const uint4*)(Wth + (size_t)n * H + chunk * 8);
            *(uint4*)(lds + lds_off(n, chunk * 8)) = v;
        }
    }
    __syncthreads();

    const int w  = tid >> 6;       // wave 0..7 -> rows 16w..16w+15
    const int l  = tid & 63;
    const int lr = l & 15;
    const int lk = (l >> 4) * 8;

    int r0 = row0 + w * 16 + lr;
    const float* a0p = Z + (size_t)(r0 < M ? r0 : M - 1) * H;

    f32x4 acc[8];
    #pragma unroll
    for (int n0 = 0; n0 < 8; ++n0)
        acc[n0] = (f32x4){0.f, 0.f, 0.f, 0.f};

    #pragma unroll
    for (int kk = 0; kk < 4; ++kk) {
        int kb = kk * 32 + lk;
        f32x4 v00 = *(const f32x4*)(a0p + kb);
        f32x4 v01 = *(const f32x4*)(a0p + kb + 4);
        short8 a0;
        uint32_t* A0 = (uint32_t*)&a0;
        A0[0] = cvtpk(v00.x, v00.y); A0[1] = cvtpk(v00.z, v00.w);
        A0[2] = cvtpk(v01.x, v01.y); A0[3] = cvtpk(v01.z, v01.w);
        #pragma unroll
        for (int n0 = 0; n0 < 8; ++n0) {
            short8 b = *(const short8*)(lds + lds_off(n0*16 + lr, kb));
            acc[n0] = __builtin_amdgcn_mfma_f32_16x16x32_bf16(a0, b, acc[n0], 0, 0, 0);
        }
    }

    float b1v[8];
    #pragma unroll
    for (int n0 = 0; n0 < 8; ++n0) b1v[n0] = addb1 ? b1[n0*16 + lr] : 0.f;

    // Quantizing epilogue. C/D: col = lane&15, row = (lane>>4)*4 + ri.
    const int rbase = row0 + w * 16;
    #pragma unroll
    for (int ri = 0; ri < 4; ++ri) {
        int gr = rbase + (l >> 4) * 4 + ri;
        float v[8];
        float am = 0.f;
        #pragma unroll
        for (int n0 = 0; n0 < 8; ++n0) {
            v[n0] = acc[n0][ri] + b1v[n0];
            am = fmaxf(am, fabsf(v[n0]));
        }
        am = fmaxf(am, __shfl_xor(am, 1));
        am = fmaxf(am, __shfl_xor(am, 2));
        am = fmaxf(am, __shfl_xor(am, 4));
        am = fmaxf(am, __shfl_xor(am, 8));
        float s = am * (1.0f / 127.0f);
        float r = 127.0f / fmaxf(am, 1e-30f);
        uint32_t lo = 0, hi = 0;
        #pragma unroll
        for (int n0 = 0; n0 < 4; ++n0) {
            uint32_t q8 = (uint32_t)fmaf(v[n0], r, 128.5f);          // 1..255
            lo |= q8 << (8 * n0);
        }
        #pragma unroll
        for (int n0 = 4; n0 < 8; ++n0) {
            uint32_t q8 = (uint32_t)fmaf(v[n0], r, 128.5f);
            hi |= q8 << (8 * (n0 - 4));
        }
        if (gr < M) {
            *(uint2*)(Out8 + (size_t)gr * H + lr * 8) = make_uint2(lo, hi);
            if (lr == 0) Sc[gr] = s;
        }
    }
}

// out[e] = relu(su*(qU-128) + si*(qI-128)) . W2 + b2   (b1 pre-folded into I)
// 8 lanes per edge, 16 int8 elems (one dwordx4) per lane per table.
// Dequant + W2 accumulate in packed f32 pairs (v_pk_fma_f32).
__device__ __forceinline__ float edge_dot16(uint4 u, uint4 i, float su, float si,
                                            const f32x2* w2p) {
    const float kk = -128.0f * (su + si);
    const f32x2 k2  = {kk, kk};
    const f32x2 su2 = {su, su};
    const f32x2 si2 = {si, si};
    f32x2 acc2 = {0.f, 0.f};
    const uint32_t* up = &u.x;
    const uint32_t* ip = &i.x;
    #pragma unroll
    for (int d = 0; d < 4; ++d) {
        f32x2 qu01 = {cvt_ub0(up[d]), cvt_ub1(up[d])};
        f32x2 qi01 = {cvt_ub0(ip[d]), cvt_ub1(ip[d])};
        f32x2 h01 = pk_fma(su2, qu01, pk_fma(si2, qi01, k2));
        h01.x = fmaxf(h01.x, 0.f); h01.y = fmaxf(h01.y, 0.f);
        acc2 = pk_fma(h01, w2p[2*d], acc2);
        f32x2 qu23 = {cvt_ub2(up[d]), cvt_ub3(up[d])};
        f32x2 qi23 = {cvt_ub2(ip[d]), cvt_ub3(ip[d])};
        f32x2 h23 = pk_fma(su2, qu23, pk_fma(si2, qi23, k2));
        h23.x = fmaxf(h23.x, 0.f); h23.y = fmaxf(h23.y, 0.f);
        acc2 = pk_fma(h23, w2p[2*d+1], acc2);
    }
    return acc2.x + acc2.y;
}

__device__ __forceinline__ float group_reduce8(float acc) {
    acc += __shfl_xor(acc, 4);
    acc += __shfl_xor(acc, 2);
    acc += __shfl_xor(acc, 1);
    return acc;
}

__global__ __launch_bounds__(256) void edge_kernel(
    const uint8_t* __restrict__ U8, const uint8_t* __restrict__ I8,
    const float* __restrict__ Us, const float* __restrict__ Is,
    const int* __restrict__ row_idx, const int* __restrict__ col_idx,
    const float* __restrict__ W2, const float* __restrict__ b2p,
    float* __restrict__ out, int E)
{
    const int l = threadIdx.x & 63;
    const int g = l >> 3;          // 8 groups of 8 lanes per wave
    const int t = l & 7;

    f32x2 w2p[8];
    #pragma unroll
    for (int j = 0; j < 8; ++j) {
        // pair (elem 2j, elem 2j+1): col = ((2j)&7)*16 + 2t + (2j>>3)
        w2p[j].x = W2[((2*j) & 7) * 16 + 2 * t + ((2*j) >> 3)];
        w2p[j].y = W2[((2*j+1) & 7) * 16 + 2 * t + ((2*j+1) >> 3)];
    }
    const float b2 = *b2p;

    const int wid = (int)((blockIdx.x * blockDim.x + threadIdx.x) >> 6);
    const int nw  = (int)((gridDim.x * blockDim.x) >> 6);
    const int stride = nw * 32;    // 4 edges per group, 8 groups per wave
    const int toff = t * 16;
    const int e0 = wid * 32 + g * 4;

    if (e0 + 3 < E) {
        int4 rp = *(const int4*)(row_idx + e0);
        int4 cp = *(const int4*)(col_idx + e0);
        for (int e = e0; e + 3 < E; e += stride) {
            int en = e + stride;
            int4 rpn = rp, cpn = cp;
            if (en + 3 < E) {
                rpn = *(const int4*)(row_idx + en);
                cpn = *(const int4*)(col_idx + en);
            }
            uint4 u0 = *(const uint4*)(U8 + (uint32_t)(rp.x * H + toff));
            uint4 i0 = *(const uint4*)(I8 + (uint32_t)(cp.x * H + toff));
            uint4 u1 = *(const uint4*)(U8 + (uint32_t)(rp.y * H + toff));
            uint4 i1 = *(const uint4*)(I8 + (uint32_t)(cp.y * H + toff));
            uint4 u2 = *(const uint4*)(U8 + (uint32_t)(rp.z * H + toff));
            uint4 i2 = *(const uint4*)(I8 + (uint32_t)(cp.z * H + toff));
            uint4 u3 = *(const uint4*)(U8 + (uint32_t)(rp.w * H + toff));
            uint4 i3 = *(const uint4*)(I8 + (uint32_t)(cp.w * H + toff));
            float su0 = Us[rp.x], si0 = Is[cp.x];
            float su1 = Us[rp.y], si1 = Is[cp.y];
            float su2 = Us[rp.z], si2 = Is[cp.z];
            float su3 = Us[rp.w], si3 = Is[cp.w];
            float a0 = group_reduce8(edge_dot16(u0, i0, su0, si0, w2p));
            float a1 = group_reduce8(edge_dot16(u1, i1, su1, si1, w2p));
            float a2 = group_reduce8(edge_dot16(u2, i2, su2, si2, w2p));
            float a3 = group_reduce8(edge_dot16(u3, i3, su3, si3, w2p));
            if (t == 0) {
                f32x4 o; o.x = a0 + b2; o.y = a1 + b2; o.z = a2 + b2; o.w = a3 + b2;
                *(f32x4*)(out + e) = o;
            }
            rp = rpn; cp = cpn;
        }
    }
    // tail (E % 4 != 0) — not hit for E = 1M
    if (wid == 0 && g == 0) {
        for (int e = (E & ~3); e < E; ++e) {
            int r = row_idx[e], c = col_idx[e];
            uint4 uv = *(const uint4*)(U8 + (uint32_t)(r * H + toff));
            uint4 iv = *(const uint4*)(I8 + (uint32_t)(c * H + toff));
            float acc = group_reduce8(edge_dot16(uv, iv, Us[r], Is[c], w2p));
            if (t == 0) out[e] = acc + b2;
        }
    }
}

extern "C" void kernel_launch(void* const* d_in, const int* in_sizes, int n_in,
                              void* d_out, int out_size, void* d_ws, size_t ws_size,
                              hipStream_t stream) {
    const float* z_user = (const float*)d_in[0];
    const float* z_item = (const float*)d_in[1];
    const int*   row_idx = (const int*)d_in[2];
    const int*   col_idx = (const int*)d_in[3];
    const float* W1 = (const float*)d_in[4];
    const float* b1 = (const float*)d_in[5];
    const float* W2 = (const float*)d_in[6];
    const float* b2 = (const float*)d_in[7];
    float* out = (float*)d_out;
    const int E = in_sizes[2];

    uint8_t* U8 = (uint8_t*)d_ws;                   // 100000*128 = 12.8 MB
    uint8_t* I8 = U8 + (size_t)NU * H;              // 50000*128  =  6.4 MB
    float*   Us = (float*)(I8 + (size_t)NI * H);    // 400 KB
    float*   Is = Us + NU;                          // 200 KB
    uint16_t* Wt = (uint16_t*)(Is + NI);            // 64 KB (16B-aligned)

    const int nub = (NU + 127) / 128;  // 782
    const int nib = (NI + 127) / 128;  // 391
    wconv_kernel<<<32, 256, 0, stream>>>(W1, Wt);
    proj_kernel<<<nub + nib, 512, 0, stream>>>(z_user, z_item, Wt, b1, U8, I8, Us, Is, nub);
    edge_kernel<<<2048, 256, 0, stream>>>(U8, I8, Us, Is, row_idx, col_idx, W2, b2, out, E);
}

// Round 10
// 62.412 us; speedup vs baseline: 1.2340x; 1.0158x over previous
//
#include <hip/hip_runtime.h>
#include <hip/hip_bf16.h>
#include <stdint.h>

#define H 128
#define NU 100000
#define NI 50000

typedef __attribute__((ext_vector_type(8))) short short8;
typedef __attribute__((ext_vector_type(4))) float f32x4;
typedef __attribute__((ext_vector_type(2))) float f32x2;

__device__ __forceinline__ uint16_t f2bf(float f) {
    uint32_t x = __float_as_uint(f);
    return (uint16_t)((x + 0x7fffu + ((x >> 16) & 1u)) >> 16);  // RNE
}
__device__ __forceinline__ uint32_t cvtpk(float lo, float hi) {
    uint32_t r;
    asm("v_cvt_pk_bf16_f32 %0, %1, %2" : "=v"(r) : "v"(lo), "v"(hi));
    return r;
}
__device__ __forceinline__ float cvt_ub0(uint32_t v) { float f; asm("v_cvt_f32_ubyte0 %0, %1" : "=v"(f) : "v"(v)); return f; }
__device__ __forceinline__ float cvt_ub1(uint32_t v) { float f; asm("v_cvt_f32_ubyte1 %0, %1" : "=v"(f) : "v"(v)); return f; }
__device__ __forceinline__ float cvt_ub2(uint32_t v) { float f; asm("v_cvt_f32_ubyte2 %0, %1" : "=v"(f) : "v"(v)); return f; }
__device__ __forceinline__ float cvt_ub3(uint32_t v) { float f; asm("v_cvt_f32_ubyte3 %0, %1" : "=v"(f) : "v"(v)); return f; }
__device__ __forceinline__ f32x2 pk_fma(f32x2 a, f32x2 b, f32x2 c) {
    f32x2 d;
    asm("v_pk_fma_f32 %0, %1, %2, %3" : "=v"(d) : "v"(a), "v"(b), "v"(c));
    return d;
}

// Swizzled byte offset into a [128][128] bf16 LDS tile (XOR bank swizzle).
__device__ __forceinline__ int lds_off(int row, int k) {
    return (row * 256 + k * 2) ^ ((row & 7) << 4);
}

// Tables are per-row-scaled biased int8, PERMUTED columns: byte position
// p = lr*8 + n0 holds column n0*16 + lr  (lr in [0,16), n0 in [0,8)).
// value = scale * (q - 128).
// Edge kernel uses 8-lane groups: lane t reads bytes [t*16, t*16+16) =
// cols { (j&7)*16 + 2t + (j>>3) : j=0..15 }.

// One-time: W1 [2H][H] f32 (k-major) -> Wt [2][H n][H k] bf16 (n-major).
// 32 blocks (2 halves x 16 slices of 8 n-rows).
__global__ __launch_bounds__(256) void wconv_kernel(
    const float* __restrict__ W1, uint16_t* __restrict__ Wt)
{
    __shared__ uint16_t lds[8][128];
    const int half = blockIdx.x >> 4;
    const int n8 = (blockIdx.x & 15) * 8;
    const float* W = W1 + (size_t)half * H * H;
    uint16_t* Out = Wt + (size_t)half * H * H;
    const int tid = threadIdx.x;

    int k = tid >> 1, noff = (tid & 1) * 4;
    f32x4 v = *(const f32x4*)(W + (size_t)k * H + n8 + noff);
    lds[noff + 0][k] = f2bf(v.x);
    lds[noff + 1][k] = f2bf(v.y);
    lds[noff + 2][k] = f2bf(v.z);
    lds[noff + 3][k] = f2bf(v.w);
    __syncthreads();
    int n = tid >> 5, c = (tid & 31) * 4;
    *(uint2*)(Out + (size_t)(n8 + n) * H + c) = *(const uint2*)&lds[n][c];
}

// Project 128 rows/block with 8 waves (16 rows/wave), quantize each output
// row to int8 with per-row scale. Full row (8 dwordx4) loaded into registers
// BEFORE any convert/MFMA -> 8-deep load pipeline per wave.
__global__ __launch_bounds__(512) void proj_kernel(
    const float* __restrict__ z_user, const float* __restrict__ z_item,
    const uint16_t* __restrict__ Wt, const float* __restrict__ b1,
    uint8_t* __restrict__ U8, uint8_t* __restrict__ I8,
    float* __restrict__ Us, float* __restrict__ Is, int nub)
{
    __shared__ char lds[32768];

    int bid = blockIdx.x;
    const float* Z; const uint16_t* Wth; uint8_t* Out8; float* Sc; int M; bool addb1;
    if (bid < nub) { Z = z_user; Wth = Wt;         Out8 = U8; Sc = Us; M = NU; addb1 = false; }
    else { bid -= nub; Z = z_item; Wth = Wt + H*H; Out8 = I8; Sc = Is; M = NI; addb1 = true; }
    const int row0 = bid * 128;
    const int tid = threadIdx.x;

    const int w  = tid >> 6;       // wave 0..7 -> rows 16w..16w+15
    const int l  = tid & 63;
    const int lr = l & 15;
    const int lk = (l >> 4) * 8;

    int r0 = row0 + w * 16 + lr;
    const float* a0p = Z + (size_t)(r0 < M ? r0 : M - 1) * H;

    // Issue ALL row loads first (independent of LDS stage below).
    f32x4 av[8];
    #pragma unroll
    for (int kk = 0; kk < 4; ++kk) {
        av[2*kk]   = *(const f32x4*)(a0p + kk * 32 + lk);
        av[2*kk+1] = *(const f32x4*)(a0p + kk * 32 + lk + 4);
    }

    // Stage B: Wt half (bf16 [n][k]) -> LDS, swizzled. 512 threads, 64B each.
    {
        int n = tid >> 2;
        #pragma unroll
        for (int p = 0; p < 4; ++p) {
            int chunk = (tid & 3) * 4 + p;
            uint4 v = *(const uint4*)(Wth + (size_t)n * H + chunk * 8);
            *(uint4*)(lds + lds_off(n, chunk * 8)) = v;
        }
    }
    __syncthreads();

    f32x4 acc[8];
    #pragma unroll
    for (int n0 = 0; n0 < 8; ++n0)
        acc[n0] = (f32x4){0.f, 0.f, 0.f, 0.f};

    #pragma unroll
    for (int kk = 0; kk < 4; ++kk) {
        int kb = kk * 32 + lk;
        f32x4 v00 = av[2*kk], v01 = av[2*kk+1];
        short8 a0;
        uint32_t* A0 = (uint32_t*)&a0;
        A0[0] = cvtpk(v00.x, v00.y); A0[1] = cvtpk(v00.z, v00.w);
        A0[2] = cvtpk(v01.x, v01.y); A0[3] = cvtpk(v01.z, v01.w);
        #pragma unroll
        for (int n0 = 0; n0 < 8; ++n0) {
            short8 b = *(const short8*)(lds + lds_off(n0*16 + lr, kb));
            acc[n0] = __builtin_amdgcn_mfma_f32_16x16x32_bf16(a0, b, acc[n0], 0, 0, 0);
        }
    }

    float b1v[8];
    #pragma unroll
    for (int n0 = 0; n0 < 8; ++n0) b1v[n0] = addb1 ? b1[n0*16 + lr] : 0.f;

    // Quantizing epilogue. C/D: col = lane&15, row = (lane>>4)*4 + ri.
    const int rbase = row0 + w * 16;
    #pragma unroll
    for (int ri = 0; ri < 4; ++ri) {
        int gr = rbase + (l >> 4) * 4 + ri;
        float v[8];
        float am = 0.f;
        #pragma unroll
        for (int n0 = 0; n0 < 8; ++n0) {
            v[n0] = acc[n0][ri] + b1v[n0];
            am = fmaxf(am, fabsf(v[n0]));
        }
        am = fmaxf(am, __shfl_xor(am, 1));
        am = fmaxf(am, __shfl_xor(am, 2));
        am = fmaxf(am, __shfl_xor(am, 4));
        am = fmaxf(am, __shfl_xor(am, 8));
        float s = am * (1.0f / 127.0f);
        float r = 127.0f / fmaxf(am, 1e-30f);
        uint32_t lo = 0, hi = 0;
        #pragma unroll
        for (int n0 = 0; n0 < 4; ++n0) {
            uint32_t q8 = (uint32_t)fmaf(v[n0], r, 128.5f);          // 1..255
            lo |= q8 << (8 * n0);
        }
        #pragma unroll
        for (int n0 = 4; n0 < 8; ++n0) {
            uint32_t q8 = (uint32_t)fmaf(v[n0], r, 128.5f);
            hi |= q8 << (8 * (n0 - 4));
        }
        if (gr < M) {
            *(uint2*)(Out8 + (size_t)gr * H + lr * 8) = make_uint2(lo, hi);
            if (lr == 0) Sc[gr] = s;
        }
    }
}

// out[e] = relu(su*(qU-128) + si*(qI-128)) . W2 + b2   (b1 pre-folded into I)
// 8 lanes per edge, 16 int8 elems (one dwordx4) per lane per table.
__device__ __forceinline__ float edge_dot16(uint4 u, uint4 i, float su, float si,
                                            const f32x2* w2p) {
    const float kk = -128.0f * (su + si);
    const f32x2 k2  = {kk, kk};
    const f32x2 su2 = {su, su};
    const f32x2 si2 = {si, si};
    f32x2 acc2 = {0.f, 0.f};
    const uint32_t* up = &u.x;
    const uint32_t* ip = &i.x;
    #pragma unroll
    for (int d = 0; d < 4; ++d) {
        f32x2 qu01 = {cvt_ub0(up[d]), cvt_ub1(up[d])};
        f32x2 qi01 = {cvt_ub0(ip[d]), cvt_ub1(ip[d])};
        f32x2 h01 = pk_fma(su2, qu01, pk_fma(si2, qi01, k2));
        h01.x = fmaxf(h01.x, 0.f); h01.y = fmaxf(h01.y, 0.f);
        acc2 = pk_fma(h01, w2p[2*d], acc2);
        f32x2 qu23 = {cvt_ub2(up[d]), cvt_ub3(up[d])};
        f32x2 qi23 = {cvt_ub2(ip[d]), cvt_ub3(ip[d])};
        f32x2 h23 = pk_fma(su2, qu23, pk_fma(si2, qi23, k2));
        h23.x = fmaxf(h23.x, 0.f); h23.y = fmaxf(h23.y, 0.f);
        acc2 = pk_fma(h23, w2p[2*d+1], acc2);
    }
    return acc2.x + acc2.y;
}

__device__ __forceinline__ float group_reduce8(float acc) {
    acc += __shfl_xor(acc, 4);
    acc += __shfl_xor(acc, 2);
    acc += __shfl_xor(acc, 1);
    return acc;
}

__global__ __launch_bounds__(256) void edge_kernel(
    const uint8_t* __restrict__ U8, const uint8_t* __restrict__ I8,
    const float* __restrict__ Us, const float* __restrict__ Is,
    const int* __restrict__ row_idx, const int* __restrict__ col_idx,
    const float* __restrict__ W2, const float* __restrict__ b2p,
    float* __restrict__ out, int E)
{
    const int l = threadIdx.x & 63;
    const int g = l >> 3;          // 8 groups of 8 lanes per wave
    const int t = l & 7;

    f32x2 w2p[8];
    #pragma unroll
    for (int j = 0; j < 8; ++j) {
        w2p[j].x = W2[((2*j) & 7) * 16 + 2 * t + ((2*j) >> 3)];
        w2p[j].y = W2[((2*j+1) & 7) * 16 + 2 * t + ((2*j+1) >> 3)];
    }
    const float b2 = *b2p;

    const int wid = (int)((blockIdx.x * blockDim.x + threadIdx.x) >> 6);
    const int nw  = (int)((gridDim.x * blockDim.x) >> 6);
    const int stride = nw * 32;    // 4 edges per group, 8 groups per wave
    const int toff = t * 16;
    const int e0 = wid * 32 + g * 4;

    if (e0 + 3 < E) {
        int4 rp = *(const int4*)(row_idx + e0);
        int4 cp = *(const int4*)(col_idx + e0);
        for (int e = e0; e + 3 < E; e += stride) {
            int en = e + stride;
            int4 rpn = rp, cpn = cp;
            if (en + 3 < E) {
                rpn = *(const int4*)(row_idx + en);
                cpn = *(const int4*)(col_idx + en);
            }
            uint4 u0 = *(const uint4*)(U8 + (uint32_t)(rp.x * H + toff));
            uint4 i0 = *(const uint4*)(I8 + (uint32_t)(cp.x * H + toff));
            uint4 u1 = *(const uint4*)(U8 + (uint32_t)(rp.y * H + toff));
            uint4 i1 = *(const uint4*)(I8 + (uint32_t)(cp.y * H + toff));
            uint4 u2 = *(const uint4*)(U8 + (uint32_t)(rp.z * H + toff));
            uint4 i2 = *(const uint4*)(I8 + (uint32_t)(cp.z * H + toff));
            uint4 u3 = *(const uint4*)(U8 + (uint32_t)(rp.w * H + toff));
            uint4 i3 = *(const uint4*)(I8 + (uint32_t)(cp.w * H + toff));
            float su0 = Us[rp.x], si0 = Is[cp.x];
            float su1 = Us[rp.y], si1 = Is[cp.y];
            float su2 = Us[rp.z], si2 = Is[cp.z];
            float su3 = Us[rp.w], si3 = Is[cp.w];
            float a0 = group_reduce8(edge_dot16(u0, i0, su0, si0, w2p));
            float a1 = group_reduce8(edge_dot16(u1, i1, su1, si1, w2p));
            float a2 = group_reduce8(edge_dot16(u2, i2, su2, si2, w2p));
            float a3 = group_reduce8(edge_dot16(u3, i3, su3, si3, w2p));
            if (t == 0) {
                f32x4 o; o.x = a0 + b2; o.y = a1 + b2; o.z = a2 + b2; o.w = a3 + b2;
                *(f32x4*)(out + e) = o;
            }
            rp = rpn; cp = cpn;
        }
    }
    // tail (E % 4 != 0) — not hit for E = 1M
    if (wid == 0 && g == 0) {
        for (int e = (E & ~3); e < E; ++e) {
            int r = row_idx[e], c = col_idx[e];
            uint4 uv = *(const uint4*)(U8 + (uint32_t)(r * H + toff));
            uint4 iv = *(const uint4*)(I8 + (uint32_t)(c * H + toff));
            float acc = group_reduce8(edge_dot16(uv, iv, Us[r], Is[c], w2p));
            if (t == 0) out[e] = acc + b2;
        }
    }
}

extern "C" void kernel_launch(void* const* d_in, const int* in_sizes, int n_in,
                              void* d_out, int out_size, void* d_ws, size_t ws_size,
                              hipStream_t stream) {
    const float* z_user = (const float*)d_in[0];
    const float* z_item = (const float*)d_in[1];
    const int*   row_idx = (const int*)d_in[2];
    const int*   col_idx = (const int*)d_in[3];
    const float* W1 = (const float*)d_in[4];
    const float* b1 = (const float*)d_in[5];
    const float* W2 = (const float*)d_in[6];
    const float* b2 = (const float*)d_in[7];
    float* out = (float*)d_out;
    const int E = in_sizes[2];

    uint8_t* U8 = (uint8_t*)d_ws;                   // 100000*128 = 12.8 MB
    uint8_t* I8 = U8 + (size_t)NU * H;              // 50000*128  =  6.4 MB
    float*   Us = (float*)(I8 + (size_t)NI * H);    // 400 KB
    float*   Is = Us + NU;                          // 200 KB
    uint16_t* Wt = (uint16_t*)(Is + NI);            // 64 KB (16B-aligned)

    const int nub = (NU + 127) / 128;  // 782
    const int nib = (NI + 127) / 128;  // 391
    wconv_kernel<<<32, 256, 0, stream>>>(W1, Wt);
    proj_kernel<<<nub + nib, 512, 0, stream>>>(z_user, z_item, Wt, b1, U8, I8, Us, Is, nub);
    edge_kernel<<<2048, 256, 0, stream>>>(U8, I8, Us, Is, row_idx, col_idx, W2, b2, out, E);
}